// Round 10
// baseline (268.205 us; speedup 1.0000x reference)
//
#include <hip/hip_runtime.h>

#define NN 50000
#define NE 800000
#define NB 6250        // NN/8 gather batches
#define NT 3125        // NN/16 mfma tiles
#define SCB 49         // ceil(NN/1024) scan blocks
#define NBK 128        // coarse buckets
#define BNODE 391      // nodes per bucket
#define BCAP 7680      // bucket capacity
#define SCAP 56        // per-block LDS stage capacity per bucket

typedef __attribute__((ext_vector_type(8))) short short8x;
typedef __attribute__((ext_vector_type(4))) float f32x4;

// ws layout (float-index offsets)
#define OFF_CNT   0LL
#define OFF_ROW   ((long long)NN)
#define OFF_RECS  (3LL*NN + 16)
#define OFF_FLAGS (35LL*NN + 16)
#define OFF_BS    (35LL*NN + 32)
#define OFF_BO    (35LL*NN + 96)
#define OFF_PK    (35LL*NN + 160)
#define OFF_FB1S  (35LL*NN + 7840)
#define OFF_FB2S  (35LL*NN + 7904)
#define OFF_F1    (36LL*NN)           // NN*160 bf16 (binbuf aliases)
#define OFF_F2    (116LL*NN)          // NN*96 bf16
#define OFF_Y2B   (164LL*NN)          // NN*32 bf16
#define OFF_S2    (180LL*NN)          // NN*32 f32
#define OFF_BCUR  (212LL*NN)          // 128 ints

__device__ __forceinline__ float ldf(const void* p, long long i, int bf16) {
  if (bf16) {
    unsigned short u = ((const unsigned short*)p)[i];
    return __uint_as_float(((unsigned)u) << 16);
  }
  return ((const float*)p)[i];
}
__device__ __forceinline__ unsigned short f2bf(float f) {
  unsigned u = __float_as_uint(f);
  unsigned r = (u + 0x7fffu + ((u >> 16) & 1u)) >> 16;
  return (unsigned short)r;
}
__device__ __forceinline__ unsigned pk2(float lo, float hi) {
  return (unsigned)f2bf(lo) | ((unsigned)f2bf(hi) << 16);
}
__device__ __forceinline__ int ldidx(const void* p, long long i, int i64) {
  return i64 ? (int)((const long long*)p)[i] : ((const int*)p)[i];
}
__device__ __forceinline__ float bflo(unsigned u) { return __uint_as_float(u << 16); }
__device__ __forceinline__ float bfhi(unsigned u) { return __uint_as_float(u & 0xffff0000u); }

// ---------------- detect dtypes ----------------
__global__ void k_detect(const void* ei, const void* x, int* flags) {
  int lane = threadIdx.x & 63;
  const int* p = (const int*)ei;
  int any = 0;
  for (int i = lane; i < 256; i += 64) any |= p[2 * i + 1];
  unsigned long long anyb = __ballot(any != 0);
  const unsigned short* q = (const unsigned short*)x;
  int cnt = 0;
  for (int i = lane; i < 256; i += 64) {
    unsigned short w = q[2 * i];
    int e = (w >> 7) & 0xff;
    if (w == 0 || (e >= 110 && e <= 140)) cnt++;
  }
  for (int m = 1; m < 64; m <<= 1) cnt += __shfl_xor(cnt, m, 64);
  if (lane == 0) {
    flags[0] = (anyb == 0ull) ? 1 : 0;
    flags[1] = (cnt >= 192) ? 1 : 0;
  }
}

// ---------------- pack BN-folded weights into MFMA B-fragment order ----------------
__global__ __launch_bounds__(256) void k_prep(
    const void* __restrict__ W1_msg, const void* __restrict__ b1_msg,
    const void* __restrict__ W1_self, const void* __restrict__ b1_self,
    const void* __restrict__ gamma, const void* __restrict__ beta,
    const void* __restrict__ mean, const void* __restrict__ var,
    const void* __restrict__ W2_msg, const void* __restrict__ b2_msg,
    const void* __restrict__ W2_self, const void* __restrict__ b2_self,
    const int* __restrict__ flags, unsigned short* __restrict__ PK,
    float* __restrict__ fb1s, float* __restrict__ fb2s) {
  int bf = flags[1];
  int t0 = blockIdx.x * 256 + threadIdx.x;
  int stride = gridDim.x * 256;
  for (int i = t0; i < 10240; i += stride) {
    int j = i & 7, L = (i >> 3) & 63, t = (i >> 9) & 3, c = i >> 11;
    int k = c * 32 + ((L >> 4) << 3) + j;
    int col = t * 16 + (L & 15);
    float sc = ldf(gamma, col, bf) * rsqrtf(ldf(var, col, bf) + 1e-5f);
    float v;
    if (k < 64) v = ldf(W1_msg, k * 64 + col, bf) * sc;
    else if (k < 128) v = ldf(W1_self, (k - 64) * 64 + col, bf) * sc;
    else if (k < 144) v = ldf(W1_msg, (64 + k - 128) * 64 + col, bf) * sc;
    else if (k == 144) v = ldf(b1_msg, col, bf) * sc;
    else v = 0.0f;
    PK[i] = f2bf(v);
  }
  for (int i = t0; i < 2048; i += stride) {
    int j = i & 7, L = (i >> 3) & 63, t = (i >> 9) & 1, c = i >> 10;
    int k = c * 32 + ((L >> 4) << 3) + j;
    int col = t * 16 + (L & 15);
    PK[10240 + i] = f2bf(ldf(W2_msg, k * 32 + col, bf));
  }
  for (int i = t0; i < 3072; i += stride) {
    int j = i & 7, L = (i >> 3) & 63, t = (i >> 9) & 1, c = i >> 10;
    int k = c * 32 + ((L >> 4) << 3) + j;
    int col = t * 16 + (L & 15);
    float v;
    if (k < 64) v = ldf(W2_self, k * 32 + col, bf);
    else if (k < 80) v = ldf(W2_msg, k * 32 + col, bf);
    else if (k == 80) v = ldf(b2_msg, col, bf);
    else v = 0.0f;
    PK[12288 + i] = f2bf(v);
  }
  for (int i = t0; i < 64; i += stride) {
    float sc = ldf(gamma, i, bf) * rsqrtf(ldf(var, i, bf) + 1e-5f);
    fb1s[i] = ldf(b1_self, i, bf) * sc + ldf(beta, i, bf) - ldf(mean, i, bf) * sc;
  }
  for (int i = t0; i < 32; i += stride) fb2s[i] = ldf(b2_self, i, bf);
}

// ---------------- phase 1: LDS-staged binning by dst/391 ----------------
__global__ __launch_bounds__(256) void k_bin(const void* __restrict__ ei,
                                             const int* __restrict__ flags,
                                             int* __restrict__ bcur,
                                             int2* __restrict__ binbuf) {
  __shared__ int2 stage[NBK][SCAP];
  __shared__ int scnt[NBK];
  __shared__ int gbase[NBK];
  int tid = threadIdx.x;
  for (int i = tid; i < NBK; i += 256) scnt[i] = 0;
  __syncthreads();
  int i64 = flags[0];
  for (long long e0 = (long long)blockIdx.x * 256; e0 < NE;
       e0 += (long long)gridDim.x * 256) {
    long long e = e0 + tid;
    if (e < NE) {
      int src = ldidx(ei, e, i64);
      int dst = ldidx(ei, NE + e, i64);
      int b = dst / BNODE;
      int dl = dst - b * BNODE;
      int2 ent = make_int2(src | (dl << 16), (int)e);
      int pos = atomicAdd(&scnt[b], 1);
      if (pos < SCAP) {
        stage[b][pos] = ent;
      } else {
        int gp = atomicAdd(&bcur[b], 1);
        binbuf[(long long)b * BCAP + gp] = ent;
      }
    }
  }
  __syncthreads();
  if (tid < NBK) {
    int cb = scnt[tid] < SCAP ? scnt[tid] : SCAP;
    gbase[tid] = atomicAdd(&bcur[tid], cb);
  }
  __syncthreads();
  for (int b = 0; b < NBK; ++b) {
    int cb = scnt[b] < SCAP ? scnt[b] : SCAP;
    for (int i = tid; i < cb; i += 256)
      binbuf[(long long)b * BCAP + gbase[b] + i] = stage[b][i];
  }
}

// ---------------- phase 1.5: per-bucket LDS histogram -> counts ----------------
__global__ __launch_bounds__(256) void k_bhist(const int* __restrict__ bcur,
                                               const int2* __restrict__ binbuf,
                                               int* __restrict__ counts) {
  __shared__ int lh[BNODE];
  int b = blockIdx.x;
  int tid = threadIdx.x;
  for (int i = tid; i < BNODE; i += 256) lh[i] = 0;
  __syncthreads();
  int cnt = bcur[b];
  for (int i = tid; i < cnt; i += 256) {
    int dl = (binbuf[(long long)b * BCAP + i].x >> 16) & 0x3FF;
    atomicAdd(&lh[dl], 1);
  }
  __syncthreads();
  int base = b * BNODE;
  int nn = NN - base < BNODE ? NN - base : BNODE;
  for (int i = tid; i < nn; i += 256) counts[base + i] = lh[i];
}

// ---------------- scan ----------------
__global__ __launch_bounds__(1024) void k_scanA(const int* __restrict__ counts,
                                                int* __restrict__ bs) {
  __shared__ int sd[1024];
  int t = threadIdx.x;
  int i = blockIdx.x * 1024 + t;
  sd[t] = (i < NN) ? counts[i] : 0;
  __syncthreads();
  for (int off = 512; off > 0; off >>= 1) {
    if (t < off) sd[t] += sd[t + off];
    __syncthreads();
  }
  if (t == 0) bs[blockIdx.x] = sd[0];
}

__global__ void k_scanB(const int* __restrict__ bs, int* __restrict__ bo) {
  int lane = threadIdx.x & 63;
  int v = (lane < SCB) ? bs[lane] : 0;
  int orig = v;
  for (int off = 1; off < 64; off <<= 1) {
    int u = __shfl_up(v, off, 64);
    if (lane >= off) v += u;
  }
  if (lane < SCB) bo[lane] = v - orig;
}

__global__ __launch_bounds__(1024) void k_scanC(const int* __restrict__ counts,
                                                const int* __restrict__ bo,
                                                int* __restrict__ row_ptr) {
  __shared__ int sd[1024];
  int t = threadIdx.x;
  int i = blockIdx.x * 1024 + t;
  int v = (i < NN) ? counts[i] : 0;
  sd[t] = v;
  __syncthreads();
  for (int off = 1; off < 1024; off <<= 1) {
    int u = (t >= off) ? sd[t - off] : 0;
    __syncthreads();
    sd[t] += u;
    __syncthreads();
  }
  int excl = sd[t] - v + bo[blockIdx.x];
  if (i < NN) row_ptr[i] = excl;
  if (i == NN - 1) row_ptr[NN] = excl + v;
}

// ---------------- phase 2: per-bucket LDS placement -> recs ----------------
__global__ __launch_bounds__(256) void k_place(const int* __restrict__ bcur,
                                               const int2* __restrict__ binbuf,
                                               const int* __restrict__ row_ptr,
                                               int2* __restrict__ recs) {
  __shared__ int2 outb[BCAP];
  __shared__ int lcur[BNODE];
  int b = blockIdx.x;
  int tid = threadIdx.x;
  int base = b * BNODE;
  int nn = NN - base < BNODE ? NN - base : BNODE;
  int rbase = row_ptr[base];
  for (int i = tid; i < nn; i += 256) lcur[i] = row_ptr[base + i] - rbase;
  __syncthreads();
  int cnt = bcur[b];
  for (int i = tid; i < cnt; i += 256) {
    int2 ent = binbuf[(long long)b * BCAP + i];
    int dl = (ent.x >> 16) & 0x3FF;
    int p = atomicAdd(&lcur[dl], 1);
    outb[p] = make_int2(ent.x & 0xFFFF, ent.y);
  }
  __syncthreads();
  for (int i = tid; i < cnt; i += 256) recs[rbase + i] = outb[i];
}

// ---------------- gather 1: 8 lanes/node, unroll-8 -> packed bf16 F1 (+F2 tail) ----------------
__global__ __launch_bounds__(256) void k_gather1(
    const void* __restrict__ x, const void* __restrict__ ea,
    const int* __restrict__ row_ptr, const int2* __restrict__ recs,
    const int* __restrict__ flags, unsigned short* __restrict__ F1,
    unsigned short* __restrict__ F2) {
  int lane = threadIdx.x & 63;
  int g = lane >> 3, c = lane & 7;
  int bf = flags[1];
  long long wid = ((long long)blockIdx.x * blockDim.x + threadIdx.x) >> 6;
  long long nw = ((long long)gridDim.x * blockDim.x) >> 6;
  for (long long b = wid; b < NB; b += nw) {
    int n = (int)(b * 8 + g);
    int beg = row_ptr[n];
    int deg = row_ptr[n + 1] - beg;
    float a0 = 0.f, a1 = 0.f, a2 = 0.f, a3 = 0.f, a4 = 0.f, a5 = 0.f, a6 = 0.f, a7 = 0.f;
    float e0 = 0.f, e1 = 0.f, e2 = 0.f, e3 = 0.f;
    if (bf) {
      const unsigned short* xs = (const unsigned short*)x;
      const unsigned short* es = (const unsigned short*)ea;
      int t = 0;
      for (; t + 8 <= deg; t += 8) {
        int2 r[8];
#pragma unroll
        for (int u = 0; u < 8; ++u) r[u] = recs[beg + t + u];
        uint4 w[8];
#pragma unroll
        for (int u = 0; u < 8; ++u)
          w[u] = *((const uint4*)(xs + ((long long)r[u].x << 6)) + c);
#pragma unroll
        for (int u = 0; u < 8; ++u) {
          a0 += bflo(w[u].x); a1 += bfhi(w[u].x);
          a2 += bflo(w[u].y); a3 += bfhi(w[u].y);
          a4 += bflo(w[u].z); a5 += bfhi(w[u].z);
          a6 += bflo(w[u].w); a7 += bfhi(w[u].w);
        }
        // ea pair-split: lanes c<4 take even edges, c>=4 take odd edges
#pragma unroll
        for (int u = 0; u < 4; ++u) {
          int eid = (c < 4) ? r[2 * u].y : r[2 * u + 1].y;
          uint2 q = *((const uint2*)(es + ((long long)eid << 4)) + (c & 3));
          e0 += bflo(q.x); e1 += bfhi(q.x);
          e2 += bflo(q.y); e3 += bfhi(q.y);
        }
      }
      for (; t < deg; ++t) {
        int2 r = recs[beg + t];
        uint4 w = *((const uint4*)(xs + ((long long)r.x << 6)) + c);
        a0 += bflo(w.x); a1 += bfhi(w.x);
        a2 += bflo(w.y); a3 += bfhi(w.y);
        a4 += bflo(w.z); a5 += bfhi(w.z);
        a6 += bflo(w.w); a7 += bfhi(w.w);
        if (c < 4) {
          uint2 q = *((const uint2*)(es + ((long long)r.y << 4)) + c);
          e0 += bflo(q.x); e1 += bfhi(q.x);
          e2 += bflo(q.y); e3 += bfhi(q.y);
        }
      }
      // combine parity halves (c and c^4 hold same column chunk)
      e0 += __shfl_xor(e0, 4, 64);
      e1 += __shfl_xor(e1, 4, 64);
      e2 += __shfl_xor(e2, 4, 64);
      e3 += __shfl_xor(e3, 4, 64);
    } else {
      const float* xf = (const float*)x;
      const float* ef = (const float*)ea;
      for (int t = 0; t < deg; ++t) {
        int2 r = recs[beg + t];
        float4 w0 = *((const float4*)(xf + ((long long)r.x << 6)) + c * 2);
        float4 w1 = *((const float4*)(xf + ((long long)r.x << 6)) + c * 2 + 1);
        a0 += w0.x; a1 += w0.y; a2 += w0.z; a3 += w0.w;
        a4 += w1.x; a5 += w1.y; a6 += w1.z; a7 += w1.w;
        if (c < 4) {
          float4 q = *((const float4*)(ef + ((long long)r.y << 4)) + c);
          e0 += q.x; e1 += q.y; e2 += q.z; e3 += q.w;
        }
      }
      float4 p0 = *((const float4*)(xf + ((long long)n << 6)) + c * 2);
      float4 p1 = *((const float4*)(xf + ((long long)n << 6)) + c * 2 + 1);
      uint4 xw = make_uint4(pk2(p0.x, p0.y), pk2(p0.z, p0.w), pk2(p1.x, p1.y),
                            pk2(p1.z, p1.w));
      *((uint4*)(F1 + (long long)n * 160 + 64) + c) = xw;  // x copy only in f32 mode
    }
    unsigned short* f1 = F1 + (long long)n * 160;
    unsigned short* f2 = F2 + (long long)n * 96;
    *((uint4*)f1 + c) = make_uint4(pk2(a0, a1), pk2(a2, a3), pk2(a4, a5), pk2(a6, a7));
    if (c < 4) {
      uint2 sp = make_uint2(pk2(e0, e1), pk2(e2, e3));
      *((uint2*)(f1 + 128) + c) = sp;
      *((uint2*)(f2 + 64) + c) = sp;
    }
    if (c == 4) {
      unsigned d = (unsigned)f2bf((float)deg);
      *((uint4*)(f1 + 144)) = make_uint4(d, 0u, 0u, 0u);
      *((uint4*)(f2 + 80)) = make_uint4(d, 0u, 0u, 0u);
    }
    if (c == 5) {
      *((uint4*)(f1 + 152)) = make_uint4(0u, 0u, 0u, 0u);
      *((uint4*)(f2 + 88)) = make_uint4(0u, 0u, 0u, 0u);
    }
  }
}

// ---------------- gemm 1 (MFMA): [Sx|x|Se|deg]@B1 + bias -> ReLU -> F2[0..64) ----------------
__global__ __launch_bounds__(256) void k_gemm1(
    const unsigned short* __restrict__ F1, const void* __restrict__ x,
    const unsigned short* __restrict__ PK, const float* __restrict__ fb1s,
    const int* __restrict__ flags, unsigned short* __restrict__ F2) {
  int lane = threadIdx.x & 63;
  int wv = threadIdx.x >> 6;
  int m = lane & 15, quad = lane >> 4;
  int bf = flags[1];
  short8x Bf[20];
#pragma unroll
  for (int s = 0; s < 20; ++s) Bf[s] = *(const short8x*)(PK + (s * 64 + lane) * 8);
  long long gw = (long long)blockIdx.x * 4 + wv;
  long long nw = (long long)gridDim.x * 4;
  for (long long tile = gw; tile < NT; tile += nw) {
    long long n0 = tile * 16;
    const unsigned short* f1 = F1 + (n0 + m) * 160 + quad * 8;
    short8x A[5];
    A[0] = *(const short8x*)(f1);
    A[1] = *(const short8x*)(f1 + 32);
    if (bf) {
      const unsigned short* xr = (const unsigned short*)x + (n0 + m) * 64 + quad * 8;
      A[2] = *(const short8x*)(xr);
      A[3] = *(const short8x*)(xr + 32);
    } else {
      A[2] = *(const short8x*)(f1 + 64);
      A[3] = *(const short8x*)(f1 + 96);
    }
    A[4] = *(const short8x*)(f1 + 128);
    f32x4 acc[4];
#pragma unroll
    for (int t = 0; t < 4; ++t) {
      float b = fb1s[t * 16 + m];
      acc[t] = (f32x4){b, b, b, b};
    }
#pragma unroll
    for (int cc = 0; cc < 5; ++cc) {
#pragma unroll
      for (int t = 0; t < 4; ++t)
        acc[t] = __builtin_amdgcn_mfma_f32_16x16x32_bf16(A[cc], Bf[cc * 4 + t], acc[t], 0, 0, 0);
    }
#pragma unroll
    for (int t = 0; t < 4; ++t) {
#pragma unroll
      for (int i = 0; i < 4; ++i) {
        float h = fmaxf(acc[t][i], 0.0f);
        F2[(n0 + quad * 4 + i) * 96 + t * 16 + m] = f2bf(h);
      }
    }
  }
}

// ---------------- gemm Y (MFMA): Y2 = F2[:,0:64] @ BY ----------------
__global__ __launch_bounds__(256) void k_gemmY(
    const unsigned short* __restrict__ F2, const unsigned short* __restrict__ PK,
    unsigned short* __restrict__ Y2B) {
  int lane = threadIdx.x & 63;
  int wv = threadIdx.x >> 6;
  int m = lane & 15, quad = lane >> 4;
  short8x Bf[4];
#pragma unroll
  for (int s = 0; s < 4; ++s) Bf[s] = *(const short8x*)(PK + 10240 + (s * 64 + lane) * 8);
  long long gw = (long long)blockIdx.x * 4 + wv;
  long long nw = (long long)gridDim.x * 4;
  for (long long tile = gw; tile < NT; tile += nw) {
    long long n0 = tile * 16;
    const unsigned short* f2 = F2 + (n0 + m) * 96 + quad * 8;
    f32x4 yacc[2];
    yacc[0] = (f32x4){0.f, 0.f, 0.f, 0.f};
    yacc[1] = (f32x4){0.f, 0.f, 0.f, 0.f};
#pragma unroll
    for (int cc = 0; cc < 2; ++cc) {
      short8x Ah = *(const short8x*)(f2 + cc * 32);
#pragma unroll
      for (int t = 0; t < 2; ++t)
        yacc[t] = __builtin_amdgcn_mfma_f32_16x16x32_bf16(Ah, Bf[cc * 2 + t], yacc[t], 0, 0, 0);
    }
#pragma unroll
    for (int t = 0; t < 2; ++t)
#pragma unroll
      for (int i = 0; i < 4; ++i)
        Y2B[(n0 + quad * 4 + i) * 32 + t * 16 + m] = f2bf(yacc[t][i]);
  }
}

// ---------------- gather 2: 8 lanes/node, unroll-8, bf16 Y2 rows -> S2 f32 ----------------
__global__ __launch_bounds__(256) void k_gather2(
    const unsigned short* __restrict__ Y2B, const int* __restrict__ row_ptr,
    const int2* __restrict__ recs, float* __restrict__ S2) {
  int lane = threadIdx.x & 63;
  int g = lane >> 3, c = lane & 7;
  long long wid = ((long long)blockIdx.x * blockDim.x + threadIdx.x) >> 6;
  long long nw = ((long long)gridDim.x * blockDim.x) >> 6;
  for (long long b = wid; b < NB; b += nw) {
    int n = (int)(b * 8 + g);
    int beg = row_ptr[n];
    int deg = row_ptr[n + 1] - beg;
    float s0 = 0.f, s1 = 0.f, s2 = 0.f, s3 = 0.f;
    int t = 0;
    for (; t + 8 <= deg; t += 8) {
      int2 r[8];
#pragma unroll
      for (int u = 0; u < 8; ++u) r[u] = recs[beg + t + u];
      uint2 q[8];
#pragma unroll
      for (int u = 0; u < 8; ++u)
        q[u] = *((const uint2*)(Y2B + (long long)r[u].x * 32) + c);
#pragma unroll
      for (int u = 0; u < 8; ++u) {
        s0 += bflo(q[u].x); s1 += bfhi(q[u].x);
        s2 += bflo(q[u].y); s3 += bfhi(q[u].y);
      }
    }
    for (; t < deg; ++t) {
      int2 r = recs[beg + t];
      uint2 q = *((const uint2*)(Y2B + (long long)r.x * 32) + c);
      s0 += bflo(q.x); s1 += bfhi(q.x);
      s2 += bflo(q.y); s3 += bfhi(q.y);
    }
    *(float4*)(S2 + (long long)n * 32 + c * 4) = make_float4(s0, s1, s2, s3);
  }
}

// ---------------- gemm 2 (MFMA): F2@B2 + S2 + fb2s -> out ----------------
__global__ __launch_bounds__(256) void k_gemm2(
    const unsigned short* __restrict__ F2, const unsigned short* __restrict__ PK,
    const float* __restrict__ fb2s, const float* __restrict__ S2,
    const int* __restrict__ flags, void* __restrict__ out) {
  int lane = threadIdx.x & 63;
  int wv = threadIdx.x >> 6;
  int m = lane & 15, quad = lane >> 4;
  int bf = flags[1];
  short8x Bf[6];
#pragma unroll
  for (int s = 0; s < 6; ++s) Bf[s] = *(const short8x*)(PK + 12288 + (s * 64 + lane) * 8);
  long long gw = (long long)blockIdx.x * 4 + wv;
  long long nw = (long long)gridDim.x * 4;
  for (long long tile = gw; tile < NT; tile += nw) {
    long long n0 = tile * 16;
    const unsigned short* f2 = F2 + (n0 + m) * 96 + quad * 8;
    short8x A[3];
#pragma unroll
    for (int cc = 0; cc < 3; ++cc) A[cc] = *(const short8x*)(f2 + cc * 32);
    f32x4 acc[2];
#pragma unroll
    for (int t = 0; t < 2; ++t) {
      float b = fb2s[t * 16 + m];
#pragma unroll
      for (int i = 0; i < 4; ++i)
        acc[t][i] = b + S2[(n0 + quad * 4 + i) * 32 + t * 16 + m];
    }
#pragma unroll
    for (int cc = 0; cc < 3; ++cc) {
#pragma unroll
      for (int t = 0; t < 2; ++t)
        acc[t] = __builtin_amdgcn_mfma_f32_16x16x32_bf16(A[cc], Bf[cc * 2 + t], acc[t], 0, 0, 0);
    }
#pragma unroll
    for (int t = 0; t < 2; ++t) {
#pragma unroll
      for (int i = 0; i < 4; ++i) {
        long long idx = (n0 + quad * 4 + i) * 32 + t * 16 + m;
        if (bf) ((unsigned short*)out)[idx] = f2bf(acc[t][i]);
        else ((float*)out)[idx] = acc[t][i];
      }
    }
  }
}

extern "C" void kernel_launch(void* const* d_in, const int* in_sizes, int n_in,
                              void* d_out, int out_size, void* d_ws, size_t ws_size,
                              hipStream_t stream) {
  const void* x = d_in[0];
  const void* ei = d_in[1];
  const void* ea = d_in[2];
  const void* W1_msg = d_in[3];
  const void* b1_msg = d_in[4];
  const void* W1_self = d_in[5];
  const void* b1_self = d_in[6];
  const void* gamma = d_in[7];
  const void* beta = d_in[8];
  const void* mean = d_in[9];
  const void* var = d_in[10];
  const void* W2_msg = d_in[11];
  const void* b2_msg = d_in[12];
  const void* W2_self = d_in[13];
  const void* b2_self = d_in[14];

  float* ws = (float*)d_ws;
  int* counts = (int*)(ws + OFF_CNT);
  int* row_ptr = (int*)(ws + OFF_ROW);
  int2* recs = (int2*)(ws + OFF_RECS);
  int* flags = (int*)(ws + OFF_FLAGS);
  int* bs = (int*)(ws + OFF_BS);
  int* bo = (int*)(ws + OFF_BO);
  unsigned short* PK = (unsigned short*)(ws + OFF_PK);
  float* fb1s = ws + OFF_FB1S;
  float* fb2s = ws + OFF_FB2S;
  unsigned short* F1 = (unsigned short*)(ws + OFF_F1);
  int2* binbuf = (int2*)(ws + OFF_F1);  // aliases F1 (dead before gather1)
  unsigned short* F2 = (unsigned short*)(ws + OFF_F2);
  unsigned short* Y2B = (unsigned short*)(ws + OFF_Y2B);
  float* S2 = ws + OFF_S2;
  int* bcur = (int*)(ws + OFF_BCUR);

  hipLaunchKernelGGL(k_detect, dim3(1), dim3(64), 0, stream, ei, x, flags);
  hipMemsetAsync(bcur, 0, NBK * sizeof(int), stream);
  hipLaunchKernelGGL(k_prep, dim3(64), dim3(256), 0, stream, W1_msg, b1_msg, W1_self,
                     b1_self, gamma, beta, mean, var, W2_msg, b2_msg, W2_self, b2_self,
                     flags, PK, fb1s, fb2s);

  hipLaunchKernelGGL(k_bin, dim3(512), dim3(256), 0, stream, ei, flags, bcur, binbuf);
  hipLaunchKernelGGL(k_bhist, dim3(NBK), dim3(256), 0, stream, bcur, binbuf, counts);
  hipLaunchKernelGGL(k_scanA, dim3(SCB), dim3(1024), 0, stream, counts, bs);
  hipLaunchKernelGGL(k_scanB, dim3(1), dim3(64), 0, stream, bs, bo);
  hipLaunchKernelGGL(k_scanC, dim3(SCB), dim3(1024), 0, stream, counts, bo, row_ptr);
  hipLaunchKernelGGL(k_place, dim3(NBK), dim3(256), 0, stream, bcur, binbuf, row_ptr,
                     recs);

  int gblocks = (NB + 3) / 4;
  hipLaunchKernelGGL(k_gather1, dim3(gblocks), dim3(256), 0, stream, x, ea, row_ptr,
                     recs, flags, F1, F2);
  int mblocks = (NT + 3) / 4;
  hipLaunchKernelGGL(k_gemm1, dim3(mblocks), dim3(256), 0, stream, F1, x, PK, fb1s,
                     flags, F2);
  hipLaunchKernelGGL(k_gemmY, dim3(mblocks), dim3(256), 0, stream, F2, PK, Y2B);
  hipLaunchKernelGGL(k_gather2, dim3(gblocks), dim3(256), 0, stream, Y2B, row_ptr, recs,
                     S2);
  hipLaunchKernelGGL(k_gemm2, dim3(mblocks), dim3(256), 0, stream, F2, PK, fb2s, S2,
                     flags, d_out);
}